// Round 1
// baseline (207.847 us; speedup 1.0000x reference)
//
#include <hip/hip_runtime.h>

#define BATCH 4
#define CH    256
#define SVOL  32768   // 32*32*32
#define SV4   8192    // SVOL/4
#define TILE  64      // spatial float4 positions per block (one wave = 1 KiB/load)
#define NCH   4       // channel chunks per block (== waves per block)
#define CCH   64      // channels per chunk

typedef float floatx4 __attribute__((ext_vector_type(4)));

// ws layout (floats):
//   [0, 1024)          coef[b][c]
//   [1024, +BATCH*SVOL) small[b][s]   (512 KB)

__global__ void __launch_bounds__(256)
coef_kernel(const float* __restrict__ istyle,
            const float* __restrict__ W_style,
            const float* __restrict__ b_style,
            const float* __restrict__ wk,
            float* __restrict__ coef) {
    int tid  = threadIdx.x;
    int wave = blockIdx.x * 4 + (tid >> 6);   // 0..1023
    int lane = tid & 63;
    int b = wave >> 8;
    int c = wave & 255;
    const float* is = istyle + b * 512;
    const float* wr = W_style + c * 512;
    float acc = 0.f;
    #pragma unroll
    for (int j = 0; j < 8; ++j) {
        int k = lane + j * 64;
        acc += is[k] * wr[k];
    }
    #pragma unroll
    for (int off = 32; off >= 1; off >>= 1)
        acc += __shfl_down(acc, off, 64);
    if (lane == 0)
        coef[b * 256 + c] = wk[c] * (acc + b_style[c] + 1.0f);
}

// One block: TILE=64 spatial float4 positions x all 256 channels.
// thread t: position = t & 63, chunk = t >> 6 (== wave id, 64 channels each).
// Every global load is a full-wave contiguous 1 KiB transaction.
// Plain (cacheable) loads: x is 134 MB < 256 MB L3, let it go L3-resident.
__global__ void __launch_bounds__(256)
reduce_c_kernel(const floatx4* __restrict__ x4,
                const float* __restrict__ coef,
                const floatx4* __restrict__ prev4,
                floatx4* __restrict__ small4) {
    __shared__ float   cf[CH];
    __shared__ floatx4 red[NCH][TILE];

    int t     = threadIdx.x;
    int pos   = t & (TILE - 1);
    int chunk = t >> 6;                       // wave id, 0..3
    int gpos  = blockIdx.x * TILE + pos;      // 0..BATCH*SV4-1
    int b     = gpos >> 13;                   // / SV4 (blocks never straddle a batch)
    int s4    = gpos & (SV4 - 1);

    cf[t] = coef[b * CH + t];                 // all 256 coef for this b
    __syncthreads();

    const floatx4* xp = x4 + (size_t)(b * CH + chunk * CCH) * SV4 + s4;
    const float*   cw = &cf[chunk * CCH];

    floatx4 acc0 = {0.f, 0.f, 0.f, 0.f};
    floatx4 acc1 = {0.f, 0.f, 0.f, 0.f};
    #pragma unroll 8
    for (int cc = 0; cc < CCH; cc += 2) {
        floatx4 v0 = xp[(size_t)cc * SV4];
        floatx4 v1 = xp[(size_t)(cc + 1) * SV4];
        acc0 += v0 * cw[cc];
        acc1 += v1 * cw[cc + 1];
    }
    red[chunk][pos] = acc0 + acc1;            // per-wave contiguous 1 KB row
    __syncthreads();

    if (t < TILE) {                           // wave 0: cross-chunk reduce + store
        floatx4 r = prev4[gpos];
        #pragma unroll
        for (int k = 0; k < NCH; ++k)
            r += red[k][t];
        small4[gpos] = r;
    }
}

// Fused 2x trilinear upsample + [1,2,1]^3/64 blur as a 3-tap separable
// stencil on the SMALL grid: even o=2j -> (5,10,1)/16, odd -> (1,10,5)/16,
// edge-clamped; product over axes, final scale 1/4096.
__global__ void __launch_bounds__(256)
upblur_kernel(const float* __restrict__ small,
              float* __restrict__ out) {
    int g  = blockIdx.x * 256 + threadIdx.x;  // 0..BATCH*64^3-1
    int xo = g & 63;
    int yo = (g >> 6) & 63;
    int zo = (g >> 12) & 63;
    int b  = g >> 18;

    int jx = xo >> 1, jy = yo >> 1, jz = zo >> 1;
    int px = xo & 1,  py = yo & 1,  pz = zo & 1;

    int xi[3] = { jx > 0 ? jx - 1 : 0, jx, jx < 31 ? jx + 1 : 31 };
    int yi[3] = { jy > 0 ? jy - 1 : 0, jy, jy < 31 ? jy + 1 : 31 };
    int zi[3] = { jz > 0 ? jz - 1 : 0, jz, jz < 31 ? jz + 1 : 31 };

    float wx[3] = { px ? 1.f : 5.f, 10.f, px ? 5.f : 1.f };
    float wy[3] = { py ? 1.f : 5.f, 10.f, py ? 5.f : 1.f };
    float wz[3] = { pz ? 1.f : 5.f, 10.f, pz ? 5.f : 1.f };

    const float* base = small + (size_t)b * SVOL;
    float acc = 0.f;
    #pragma unroll
    for (int a = 0; a < 3; ++a) {
        const float* pzrow = base + zi[a] * 1024;
        float accy = 0.f;
        #pragma unroll
        for (int c = 0; c < 3; ++c) {
            const float* pyrow = pzrow + yi[c] * 32;
            float row = wx[0] * pyrow[xi[0]] + wx[1] * pyrow[xi[1]] + wx[2] * pyrow[xi[2]];
            accy += wy[c] * row;
        }
        acc += wz[a] * accy;
    }
    out[g] = acc * (1.0f / 4096.0f);
}

extern "C" void kernel_launch(void* const* d_in, const int* in_sizes, int n_in,
                              void* d_out, int out_size, void* d_ws, size_t ws_size,
                              hipStream_t stream) {
    const float* x       = (const float*)d_in[0];
    const float* prev    = (const float*)d_in[1];
    const float* istyle  = (const float*)d_in[2];
    const float* W_style = (const float*)d_in[3];
    const float* b_style = (const float*)d_in[4];
    const float* wk      = (const float*)d_in[5];  // conv_weight flat = (C,)
    float* ws    = (float*)d_ws;
    float* coef  = ws;          // 1024 floats
    float* small = ws + 1024;   // BATCH*SVOL floats

    coef_kernel<<<256, 256, 0, stream>>>(istyle, W_style, b_style, wk, coef);

    reduce_c_kernel<<<BATCH * SV4 / TILE, 256, 0, stream>>>(
        (const floatx4*)x, coef, (const floatx4*)prev, (floatx4*)small);

    upblur_kernel<<<BATCH * 64 * 64 * 64 / 256, 256, 0, stream>>>(small, (float*)d_out);
}

// Round 2
// 196.291 us; speedup vs baseline: 1.0589x; 1.0589x over previous
//
#include <hip/hip_runtime.h>

#define BATCH 4
#define CH    256
#define SVOL  32768   // 32*32*32
#define SV4   8192    // SVOL/4
#define TILE  32      // spatial float4 positions per block
#define NCH   8       // channel chunks per block (8 x 32 channels)
#define CCH   32      // channels per chunk

typedef float floatx4 __attribute__((ext_vector_type(4)));

// ws layout (floats):
//   [0, 1024)          coef[b][c]
//   [1024, +BATCH*SVOL) small[b][s]   (512 KB)

__global__ void __launch_bounds__(256)
coef_kernel(const float* __restrict__ istyle,
            const float* __restrict__ W_style,
            const float* __restrict__ b_style,
            const float* __restrict__ wk,
            float* __restrict__ coef) {
    int tid  = threadIdx.x;
    int wave = blockIdx.x * 4 + (tid >> 6);   // 0..1023
    int lane = tid & 63;
    int b = wave >> 8;
    int c = wave & 255;
    const float* is = istyle + b * 512;
    const float* wr = W_style + c * 512;
    float acc = 0.f;
    #pragma unroll
    for (int j = 0; j < 8; ++j) {
        int k = lane + j * 64;
        acc += is[k] * wr[k];
    }
    #pragma unroll
    for (int off = 32; off >= 1; off >>= 1)
        acc += __shfl_down(acc, off, 64);
    if (lane == 0)
        coef[b * 256 + c] = wk[c] * (acc + b_style[c] + 1.0f);
}

// Previous-session geometry (1024 blocks = 4 blocks/CU = 16 waves/CU) which
// measured fastest; nontemporal x loads (streamed once, keep out of cache);
// dual accumulators for ILP. 512B-per-half-wave segments are fully coalesced.
__global__ void __launch_bounds__(256)
reduce_c_kernel(const floatx4* __restrict__ x4,
                const float* __restrict__ coef,
                const floatx4* __restrict__ prev4,
                floatx4* __restrict__ small4) {
    __shared__ float   cf[CH];
    __shared__ floatx4 red[NCH][TILE];

    int t     = threadIdx.x;
    int pos   = t & (TILE - 1);
    int chunk = t >> 5;                       // 0..7
    int gpos  = blockIdx.x * TILE + pos;      // 0..BATCH*SV4-1
    int b     = gpos >> 13;                   // / SV4 (blocks never straddle a batch)
    int s4    = gpos & (SV4 - 1);

    cf[t] = coef[b * CH + t];                 // all 256 coef for this b
    __syncthreads();

    const floatx4* xp = x4 + (size_t)(b * CH + chunk * CCH) * SV4 + s4;
    const float*   cw = &cf[chunk * CCH];

    floatx4 acc0 = {0.f, 0.f, 0.f, 0.f};
    floatx4 acc1 = {0.f, 0.f, 0.f, 0.f};
    #pragma unroll 8
    for (int cc = 0; cc < CCH; cc += 2) {
        floatx4 v0 = __builtin_nontemporal_load(&xp[(size_t)cc * SV4]);
        floatx4 v1 = __builtin_nontemporal_load(&xp[(size_t)(cc + 1) * SV4]);
        acc0 += v0 * cw[cc];
        acc1 += v1 * cw[cc + 1];
    }
    red[chunk][pos] = acc0 + acc1;
    __syncthreads();

    if (t < TILE) {                           // tiny tail: 8 LDS reads + 1 store
        floatx4 r = prev4[gpos];
        #pragma unroll
        for (int k = 0; k < NCH; ++k)
            r += red[k][t];
        small4[gpos] = r;
    }
}

// Fused 2x trilinear upsample + [1,2,1]^3/64 blur as a 3-tap separable
// stencil on the SMALL grid. 4 consecutive x-outputs per thread:
// they share taps r[2u-1..2u+2], so 4 loads per (z,y) row instead of 12,
// and a coalesced float4 store (1 KiB/wave).
//   out(4u+0) = 5a+10b+ c   (a=r[2u-1], b=r[2u], c=r[2u+1], d=r[2u+2])
//   out(4u+1) =  a+10b+5c
//   out(4u+2) = 5b+10c+ d
//   out(4u+3) =  b+10c+5d
// then wy/wz (parity 5/10/1 vs 1/10/5) over y,z; scale 1/4096. Edge-clamped.
__global__ void __launch_bounds__(256)
upblur_kernel(const float* __restrict__ small,
              floatx4* __restrict__ out4) {
    int g4 = blockIdx.x * 256 + threadIdx.x;  // 0..BATCH*64*64*16-1
    int u  = g4 & 15;                         // x-quad index (4 outputs)
    int yo = (g4 >> 4) & 63;
    int zo = (g4 >> 10) & 63;
    int b  = g4 >> 16;

    int jy = yo >> 1, jz = zo >> 1;
    int py = yo & 1,  pz = zo & 1;

    int yi[3] = { jy > 0 ? jy - 1 : 0, jy, jy < 31 ? jy + 1 : 31 };
    int zi[3] = { jz > 0 ? jz - 1 : 0, jz, jz < 31 ? jz + 1 : 31 };
    float wy[3] = { py ? 1.f : 5.f, 10.f, py ? 5.f : 1.f };
    float wz[3] = { pz ? 1.f : 5.f, 10.f, pz ? 5.f : 1.f };

    int xa = 2 * u - 1; if (xa < 0) xa = 0;
    int xb = 2 * u;
    int xc = 2 * u + 1;
    int xd = 2 * u + 2; if (xd > 31) xd = 31;

    const float* base = small + (size_t)b * SVOL;
    floatx4 acc = {0.f, 0.f, 0.f, 0.f};
    #pragma unroll
    for (int a = 0; a < 3; ++a) {
        const float* zrow = base + zi[a] * 1024;
        floatx4 accy = {0.f, 0.f, 0.f, 0.f};
        #pragma unroll
        for (int c = 0; c < 3; ++c) {
            const float* yrow = zrow + yi[c] * 32;
            float ra = yrow[xa], rb = yrow[xb], rc = yrow[xc], rd = yrow[xd];
            floatx4 rr = { 5.f * ra + 10.f * rb + rc,
                           ra + 10.f * rb + 5.f * rc,
                           5.f * rb + 10.f * rc + rd,
                           rb + 10.f * rc + 5.f * rd };
            accy += wy[c] * rr;
        }
        acc += wz[a] * accy;
    }
    out4[g4] = acc * (1.0f / 4096.0f);
}

extern "C" void kernel_launch(void* const* d_in, const int* in_sizes, int n_in,
                              void* d_out, int out_size, void* d_ws, size_t ws_size,
                              hipStream_t stream) {
    const float* x       = (const float*)d_in[0];
    const float* prev    = (const float*)d_in[1];
    const float* istyle  = (const float*)d_in[2];
    const float* W_style = (const float*)d_in[3];
    const float* b_style = (const float*)d_in[4];
    const float* wk      = (const float*)d_in[5];  // conv_weight flat = (C,)
    float* ws    = (float*)d_ws;
    float* coef  = ws;          // 1024 floats
    float* small = ws + 1024;   // BATCH*SVOL floats

    coef_kernel<<<256, 256, 0, stream>>>(istyle, W_style, b_style, wk, coef);

    reduce_c_kernel<<<BATCH * SV4 / TILE, 256, 0, stream>>>(
        (const floatx4*)x, coef, (const floatx4*)prev, (floatx4*)small);

    upblur_kernel<<<BATCH * 64 * 64 * 16 / 256, 256, 0, stream>>>(
        small, (floatx4*)d_out);
}

// Round 3
// 195.305 us; speedup vs baseline: 1.0642x; 1.0051x over previous
//
#include <hip/hip_runtime.h>

#define BATCH 4
#define CH    256
#define SVOL  32768   // 32*32*32
#define SV4   8192    // SVOL/4
#define TILE  32      // spatial float4 positions per block
#define NCH   8       // channel chunks per block (8 x 32 channels)
#define CCH   32      // channels per chunk

typedef float floatx4 __attribute__((ext_vector_type(4)));

// ws layout (floats):
//   [0, 1024)          coef[b][c]
//   [1024, +BATCH*SVOL) small[b][s]   (512 KB)

__global__ void __launch_bounds__(256)
coef_kernel(const float* __restrict__ istyle,
            const float* __restrict__ W_style,
            const float* __restrict__ b_style,
            const float* __restrict__ wk,
            float* __restrict__ coef) {
    int tid  = threadIdx.x;
    int wave = blockIdx.x * 4 + (tid >> 6);   // 0..1023
    int lane = tid & 63;
    int b = wave >> 8;
    int c = wave & 255;
    const float* is = istyle + b * 512;
    const float* wr = W_style + c * 512;
    float acc = 0.f;
    #pragma unroll
    for (int j = 0; j < 8; ++j) {
        int k = lane + j * 64;
        acc += is[k] * wr[k];
    }
    #pragma unroll
    for (int off = 32; off >= 1; off >>= 1)
        acc += __shfl_down(acc, off, 64);
    if (lane == 0)
        coef[b * 256 + c] = wk[c] * (acc + b_style[c] + 1.0f);
}

// 1024 blocks = 4 blocks/CU exactly resident (launch_bounds(256,4) pins
// VGPR<=128 so occupancy holds). nt loads: x is stream-once, keep it from
// thrashing L2/L3. 4 accumulators for ILP; prev4 load hoisted above the
// channel loop so its latency hides under the 32 channel loads.
__global__ void __launch_bounds__(256, 4)
reduce_c_kernel(const floatx4* __restrict__ x4,
                const float* __restrict__ coef,
                const floatx4* __restrict__ prev4,
                floatx4* __restrict__ small4) {
    __shared__ float   cf[CH];
    __shared__ floatx4 red[NCH][TILE];

    int t     = threadIdx.x;
    int pos   = t & (TILE - 1);
    int chunk = t >> 5;                       // 0..7
    int gpos  = blockIdx.x * TILE + pos;      // 0..BATCH*SV4-1
    int b     = gpos >> 13;                   // / SV4 (blocks never straddle a batch)
    int s4    = gpos & (SV4 - 1);

    cf[t] = coef[b * CH + t];                 // all 256 coef for this b

    floatx4 pv = {0.f, 0.f, 0.f, 0.f};       // epilogue prev, issued early
    if (t < TILE) pv = prev4[gpos];

    __syncthreads();

    const floatx4* xp = x4 + (size_t)(b * CH + chunk * CCH) * SV4 + s4;
    const float*   cw = &cf[chunk * CCH];

    floatx4 acc0 = {0.f, 0.f, 0.f, 0.f};
    floatx4 acc1 = {0.f, 0.f, 0.f, 0.f};
    floatx4 acc2 = {0.f, 0.f, 0.f, 0.f};
    floatx4 acc3 = {0.f, 0.f, 0.f, 0.f};
    #pragma unroll 4
    for (int cc = 0; cc < CCH; cc += 4) {
        floatx4 v0 = __builtin_nontemporal_load(&xp[(size_t)cc * SV4]);
        floatx4 v1 = __builtin_nontemporal_load(&xp[(size_t)(cc + 1) * SV4]);
        floatx4 v2 = __builtin_nontemporal_load(&xp[(size_t)(cc + 2) * SV4]);
        floatx4 v3 = __builtin_nontemporal_load(&xp[(size_t)(cc + 3) * SV4]);
        acc0 += v0 * cw[cc];
        acc1 += v1 * cw[cc + 1];
        acc2 += v2 * cw[cc + 2];
        acc3 += v3 * cw[cc + 3];
    }
    red[chunk][pos] = (acc0 + acc1) + (acc2 + acc3);
    __syncthreads();

    if (t < TILE) {                           // tiny tail: 8 LDS reads + 1 store
        floatx4 r = pv;
        #pragma unroll
        for (int k = 0; k < NCH; ++k)
            r += red[k][t];
        small4[gpos] = r;
    }
}

// Fused 2x trilinear upsample + [1,2,1]^3/64 blur as a 3-tap separable
// stencil on the SMALL grid. 4 consecutive x-outputs per thread share the
// taps r[2u-1..2u+2]: 4 loads per (z,y) row, coalesced float4 nt store.
//   out(4u+0) = 5a+10b+ c   (a=r[2u-1], b=r[2u], c=r[2u+1], d=r[2u+2])
//   out(4u+1) =  a+10b+5c
//   out(4u+2) = 5b+10c+ d
//   out(4u+3) =  b+10c+5d
// then wy/wz (parity 5/10/1 vs 1/10/5) over y,z; scale 1/4096. Edge-clamped.
__global__ void __launch_bounds__(256)
upblur_kernel(const float* __restrict__ small,
              floatx4* __restrict__ out4) {
    int g4 = blockIdx.x * 256 + threadIdx.x;  // 0..BATCH*64*64*16-1
    int u  = g4 & 15;                         // x-quad index (4 outputs)
    int yo = (g4 >> 4) & 63;
    int zo = (g4 >> 10) & 63;
    int b  = g4 >> 16;

    int jy = yo >> 1, jz = zo >> 1;
    int py = yo & 1,  pz = zo & 1;

    int yi[3] = { jy > 0 ? jy - 1 : 0, jy, jy < 31 ? jy + 1 : 31 };
    int zi[3] = { jz > 0 ? jz - 1 : 0, jz, jz < 31 ? jz + 1 : 31 };
    float wy[3] = { py ? 1.f : 5.f, 10.f, py ? 5.f : 1.f };
    float wz[3] = { pz ? 1.f : 5.f, 10.f, pz ? 5.f : 1.f };

    int xa = 2 * u - 1; if (xa < 0) xa = 0;
    int xb = 2 * u;
    int xc = 2 * u + 1;
    int xd = 2 * u + 2; if (xd > 31) xd = 31;

    const float* base = small + (size_t)b * SVOL;
    floatx4 acc = {0.f, 0.f, 0.f, 0.f};
    #pragma unroll
    for (int a = 0; a < 3; ++a) {
        const float* zrow = base + zi[a] * 1024;
        floatx4 accy = {0.f, 0.f, 0.f, 0.f};
        #pragma unroll
        for (int c = 0; c < 3; ++c) {
            const float* yrow = zrow + yi[c] * 32;
            float ra = yrow[xa], rb = yrow[xb], rc = yrow[xc], rd = yrow[xd];
            floatx4 rr = { 5.f * ra + 10.f * rb + rc,
                           ra + 10.f * rb + 5.f * rc,
                           5.f * rb + 10.f * rc + rd,
                           rb + 10.f * rc + 5.f * rd };
            accy += wy[c] * rr;
        }
        acc += wz[a] * accy;
    }
    __builtin_nontemporal_store(acc * (1.0f / 4096.0f), &out4[g4]);
}

extern "C" void kernel_launch(void* const* d_in, const int* in_sizes, int n_in,
                              void* d_out, int out_size, void* d_ws, size_t ws_size,
                              hipStream_t stream) {
    const float* x       = (const float*)d_in[0];
    const float* prev    = (const float*)d_in[1];
    const float* istyle  = (const float*)d_in[2];
    const float* W_style = (const float*)d_in[3];
    const float* b_style = (const float*)d_in[4];
    const float* wk      = (const float*)d_in[5];  // conv_weight flat = (C,)
    float* ws    = (float*)d_ws;
    float* coef  = ws;          // 1024 floats
    float* small = ws + 1024;   // BATCH*SVOL floats

    coef_kernel<<<256, 256, 0, stream>>>(istyle, W_style, b_style, wk, coef);

    reduce_c_kernel<<<BATCH * SV4 / TILE, 256, 0, stream>>>(
        (const floatx4*)x, coef, (const floatx4*)prev, (floatx4*)small);

    upblur_kernel<<<BATCH * 64 * 64 * 16 / 256, 256, 0, stream>>>(
        small, (floatx4*)d_out);
}